// Round 12
// baseline (258.858 us; speedup 1.0000x reference)
//
#include <hip/hip_runtime.h>

typedef unsigned short u16;
typedef unsigned int   u32;
typedef unsigned long long u64;
typedef __bf16 bf16;
typedef float f32x16  __attribute__((ext_vector_type(16)));
typedef bf16  bf16x8  __attribute__((ext_vector_type(8)));

__device__ __forceinline__ float bf2f(u16 u){ return (float)__builtin_bit_cast(bf16,u); }
__device__ __forceinline__ u16   f2bf(float f){ return __builtin_bit_cast(u16,(bf16)f); }
__device__ __forceinline__ u32   pkbf(float a,float b){ return (u32)f2bf(a)|((u32)f2bf(b)<<16); }

#define NROWS 32768

// ---- basis: 8 bf16 slots, NO c6 (folded into B); d2(u)=d1(1-u), d0=w1^3, d3=u^3 ----
__device__ __forceinline__ uint4 basis_pk(float x)
{
  float tp  = __fmaf_rn(x, 2.5f, 5.5f);
  float tpc = fminf(fmaxf(tp, -1.0f), 12.0f);   // out-of-range -> window miss -> zeros
  float fi  = floorf(tpc);
  float uu  = tpc - fi;
  int   i0  = (int)fi;
  float u2 = uu*uu, u3 = u2*uu, w1 = 1.0f-uu, w2 = w1*w1, w3 = w2*w1;
  float d1 = __fmaf_rn(3.0f, u3, __fmaf_rn(-6.0f, u2, 4.0f));
  float d2 = __fmaf_rn(3.0f, w3, __fmaf_rn(-6.0f, w2, 4.0f));
  u64 dpk = (u64)pkbf(w3, d1) | ((u64)pkbf(d2, u3) << 32);
  int ss = i0*16 - 48;
  u64 A  = dpk << (ss & 63);
  u64 Bv = dpk >> ((64-ss) & 63);
  u64 Cv = dpk << ((ss-64) & 63);
  u64 Dv = dpk >> ((-ss) & 63);
  u64 lo = (ss>=0 && ss<64)   ? A  : ((ss<0 && ss>-64) ? Dv : 0ull);
  u64 hi = (ss>=64 && ss<128) ? Cv : ((ss>0 && ss<64)  ? Bv : 0ull);
  uint4 r; r.x=(u32)lo; r.y=(u32)(lo>>32); r.z=(u32)hi; r.w=(u32)(hi>>32);
  return r;
}

// ---------------- weight prep: all layers fmt0 (32x32x16 fragment order) ----------------
// 16-feat chunk = [16 silu | 128 basis] = 9 ksteps of K=16
// dest: ((kstep*NT32 + nt)*64 + lane)*8 + j ; o = nt*32+(lane&31); k-oct = lane>>5
struct PrepArgs {
  const float* bw[7]; const float* sw[7]; const float* sc[7];
  u16* w[7];
  int cin[7]; int coutr[7]; int ntsh[7];
  u32 elems[7];
};

__global__ __launch_bounds__(256) void prep_kernel(PrepArgs pa)
{
  u32 idx = blockIdx.x*256 + threadIdx.x;
  int L = 0;
  u32 off = idx;
  while (L < 6 && off >= pa.elems[L]) { off -= pa.elems[L]; ++L; }
  int j    = off & 7;
  int lane = (off>>3) & 63;
  u32 tl   = off >> 9;
  int ntsh = pa.ntsh[L];
  u32 kstep = tl >> ntsh;
  int nt   = (int)(tl & ((1u<<ntsh)-1u));
  int o    = nt*32 + (lane&31);
  int koct = lane>>5;
  u32 c = kstep/9u; int r = (int)(kstep - c*9u);
  int i, g = 0; bool sil;
  if (r == 0){ i = (int)c*16 + koct*8 + j; sil = true; }
  else       { i = (int)c*16 + (r-1)*2 + koct; g = j; sil = false; }
  float v = 0.f;
  if (o < pa.coutr[L]) {
    size_t e = (size_t)o*pa.cin[L] + i;
    v = sil ? pa.bw[L][e] : pa.sw[L][e*8+g]*pa.sc[L][e]*0.16666666666666666f;
  }
  pa.w[L][off] = f2bf(v);
}

// ---------------- fused network: one block = 64 rows through all 7 layers ----------------
struct WP { const u16 *w0,*w1,*w2,*w3,*w4,*w5,*w6; };

// SRC: 1 = global x, 0 = LDS (stride SS). DST: 0 = LDS (stride DS), 1 = adv global (<18), 2 = val global (col0)
template<int CIN,int COUT,int SRC,int DST>
__device__ __forceinline__ void layer_pass(
    const float* __restrict__ gsrc, const float* lsrc, int SS,
    const u16* __restrict__ W,
    float* ldst, int DS, float* __restrict__ gdst,
    u32* sbuf, int tid, int b0)
{
  constexpr int NT32 = COUT/32;
  constexpr int CFW  = (NT32>=8)? 2 : 1;
  constexpr int CGN  = NT32/CFW;            // col groups
  constexpr int NACT = 2*CGN;               // active waves = 2 rg x CGN cg
  constexpr int NCH  = CIN/16;
  constexpr int TOTK = NCH*9;
  constexpr int SROW=12, BROW=68, BOFF=64*SROW, CHUNK=BOFF+64*BROW; // 5120 dw

  const int wave = tid>>6, lane = tid&63, m32 = lane&31, koct = lane>>5;
  const bool act = wave < NACT;
  const int rg = wave / CGN;
  const int cg = wave % CGN;
  const int ctbase = cg*CFW;

  f32x16 acc[CFW];
#pragma unroll
  for (int c=0;c<CFW;++c)
#pragma unroll
    for (int e=0;e<16;++e) acc[c][e]=0.f;

  bf16x8 bbuf[3][CFW];
  auto loadB = [&](int kstep, int slot){
    if (act && kstep < TOTK){
#pragma unroll
      for (int cf=0; cf<CFW; ++cf)
        bbuf[slot][cf] = *(const bf16x8*)(W + (((size_t)kstep*NT32 + ctbase+cf)*64 + lane)*8);
    }
  };
  loadB(0,0); loadB(1,1);

  auto stage = [&](int kc, u32* dstb){      // all 16 waves: 1024 tasks = 1/thread
    int row = tid>>4, f = tid&15;
    float x = (SRC==1) ? gsrc[(size_t)(b0+row)*CIN + kc*16 + f]
                       : lsrc[row*SS + kc*16 + f];
    float s = x * __builtin_amdgcn_rcpf(1.0f + __expf(-x));
    ((u16*)dstb)[row*(SROW*2) + f] = f2bf(s);
    *(uint4*)&dstb[BOFF + row*BROW + f*4] = basis_pk(x);
  };

  stage(0, sbuf);
  __syncthreads();
  for (int kc=0; kc<NCH; ++kc){
    u32* cur = sbuf + (kc&1)*CHUNK;
    if (kc+1 < NCH) stage(kc+1, sbuf + ((kc+1)&1)*CHUNK);
    if (act){
      const int row = rg*32 + m32;
#pragma unroll
      for (int r=0; r<9; ++r){
        loadB(kc*9+r+2, (r+2)%3);          // static slot: zero-move rotation (9%3==0)
        bf16x8 af;
        if (r==0) af = __builtin_bit_cast(bf16x8, *(const uint4*)&cur[row*SROW + koct*4]);
        else      af = __builtin_bit_cast(bf16x8, *(const uint4*)&cur[BOFF + row*BROW + ((r-1)*2+koct)*4]);
#pragma unroll
        for (int cf=0; cf<CFW; ++cf)
          acc[cf] = __builtin_amdgcn_mfma_f32_32x32x16_bf16(af, bbuf[r%3][cf], acc[cf],0,0,0);
      }
    }
    __syncthreads();
  }

  // epilogue: 32x32 C/D col=lane&31, row=(reg&3)+8*(reg>>2)+4*(lane>>5)  [m74/m101]
  if (act){
#pragma unroll
    for (int cf=0; cf<CFW; ++cf)
#pragma unroll
      for (int reg=0; reg<16; ++reg){
        int rl   = (reg&3) + 8*(reg>>2) + 4*koct;
        int grow = rg*32 + rl;
        int col  = (ctbase+cf)*32 + m32;
        if constexpr (DST==0)       ldst[grow*DS + col] = acc[cf][reg];
        else if constexpr (DST==1){ if (col < 18) gdst[(size_t)(b0+grow)*18 + col] = acc[cf][reg]; }
        else                      { if (col == 0) gdst[b0+grow] = acc[cf][reg]; }
      }
  }
}

__global__ __launch_bounds__(1024,4) void fused_kernel(
    const float* __restrict__ x, WP wp,
    float* __restrict__ adv, float* __restrict__ val)
{
  __shared__ float hbuf[64*257];                 // 65792 B (h0/h1/h2 in-place)
  __shared__ float hA[64*65];                    // 16640 B (a3 / v5)
  __shared__ u32   sbuf[2*(64*12+64*68)];        // 40960 B staging dbuf
  const int tid = threadIdx.x, b0 = blockIdx.x*64;

  layer_pass<128,256,1,0>(x, nullptr,0,  wp.w0, hbuf,257, nullptr, sbuf, tid, b0);
  __syncthreads();
  layer_pass<256,256,0,0>(nullptr, hbuf,257, wp.w1, hbuf,257, nullptr, sbuf, tid, b0);
  __syncthreads();
  layer_pass<256, 64,0,0>(nullptr, hbuf,257, wp.w2, hbuf,257, nullptr, sbuf, tid, b0); // h2 -> cols 0..63
  __syncthreads();
  layer_pass< 64, 64,0,0>(nullptr, hbuf,257, wp.w3, hA,65, nullptr, sbuf, tid, b0);
  __syncthreads();
  layer_pass< 64, 32,0,1>(nullptr, hA,65,   wp.w4, nullptr,0, adv, sbuf, tid, b0);
  __syncthreads();
  layer_pass< 64, 64,0,0>(nullptr, hbuf,257, wp.w5, hA,65, nullptr, sbuf, tid, b0);
  __syncthreads();
  layer_pass< 64, 32,0,2>(nullptr, hA,65,   wp.w6, nullptr,0, val, sbuf, tid, b0);
}

extern "C" void kernel_launch(void* const* d_in, const int* in_sizes, int n_in,
                              void* d_out, int out_size, void* d_ws, size_t ws_size,
                              hipStream_t stream)
{
  (void)in_sizes; (void)n_in; (void)out_size; (void)ws_size;
  char* ws = (char*)d_ws;

  // W sizes (bytes): TOTK x NT32 x 64 lanes x 8 x 2B
  const size_t wbytes[7] = {589824u, 1179648u, 294912u, 73728u, 36864u, 73728u, 36864u};
  u16* W[7];
  { size_t off = 0; for (int l=0;l<7;++l){ W[l] = (u16*)(ws+off); off += wbytes[l]; } }

  PrepArgs pa;
  const int cins[7]  = {128,256,256,64,64,64,64};
  const int coutr[7] = {256,256,64,64,18,64,1};
  const int ntsh[7]  = {3,3,1,1,0,1,0};           // log2(NT32), COUT padded to 32 for L4/L6
  const u32 elems[7] = {294912u,589824u,147456u,36864u,18432u,36864u,18432u}; // sum = 4464*256
  for (int l=0;l<7;++l){
    pa.bw[l] = (const float*)d_in[1+3*l];
    pa.sw[l] = (const float*)d_in[2+3*l];
    pa.sc[l] = (const float*)d_in[3+3*l];
    pa.w[l]  = W[l];
    pa.cin[l]=cins[l]; pa.coutr[l]=coutr[l]; pa.ntsh[l]=ntsh[l];
    pa.elems[l]=elems[l];
  }
  prep_kernel<<<4464, 256, 0, stream>>>(pa);

  WP wp{W[0],W[1],W[2],W[3],W[4],W[5],W[6]};
  float* out_adv = (float*)d_out;
  float* out_val = (float*)d_out + (size_t)NROWS*18;
  fused_kernel<<<NROWS/64, 1024, 0, stream>>>((const float*)d_in[0], wp, out_adv, out_val);
}